// Round 1
// baseline (7980.727 us; speedup 1.0000x reference)
//
#include <hip/hip_runtime.h>
#include <hip/hip_bf16.h>

#define DIV_UP(a,b) (((a)+(b)-1)/(b))

// ---------------------------------------------------------------------------
// Transpose conv weights OIHW [O,I,3,3] -> [I*9][O] so the inner oc loop
// reads consecutive block-uniform addresses (scalar s_load batches).
// ---------------------------------------------------------------------------
__global__ void transpose_w_kernel(const float* __restrict__ src,
                                   float* __restrict__ dst, int O, int I) {
    int t = blockIdx.x * blockDim.x + threadIdx.x;
    int total = O * I * 9;
    if (t >= total) return;
    int oc = t % O;
    int r  = t / O;        // r = c*9 + q
    int q  = r % 9;
    int c  = r / 9;
    dst[t] = src[(oc * I + c) * 9 + q];
}

// ---------------------------------------------------------------------------
// conv1: fp32 NCHW [B,3,128,128] -> bf16 [B,64,64,64], stride 2 pad 1, ReLU
// thread = (b, oh, ow), all 64 oc in registers. block (64,4), grid (16, B)
// ---------------------------------------------------------------------------
__global__ __launch_bounds__(256, 4) void conv1_kernel(
    const float* __restrict__ in, const float* __restrict__ wt /*[27][64]*/,
    const float* __restrict__ bias, __hip_bfloat16* __restrict__ out) {
    const int ow = threadIdx.x;                      // 0..63
    const int oh = blockIdx.x * 4 + threadIdx.y;     // 0..63
    const int b  = blockIdx.y;
    float acc[64];
#pragma unroll
    for (int oc = 0; oc < 64; ++oc) acc[oc] = bias[oc];
    for (int c = 0; c < 3; ++c) {
        const float* bp = in + ((size_t)(b * 3 + c)) * 128 * 128;
#pragma unroll
        for (int kh = 0; kh < 3; ++kh) {
            int ih = oh * 2 - 1 + kh;
            bool vh = (unsigned)ih < 128u;
#pragma unroll
            for (int kw = 0; kw < 3; ++kw) {
                int iw = ow * 2 - 1 + kw;
                bool v = vh && ((unsigned)iw < 128u);
                float x = v ? bp[ih * 128 + iw] : 0.f;
                const float* w = wt + (c * 9 + kh * 3 + kw) * 64;
#pragma unroll
                for (int oc = 0; oc < 64; ++oc) acc[oc] = fmaf(x, w[oc], acc[oc]);
            }
        }
    }
    size_t obase = ((size_t)b * 64) * 64 * 64 + (size_t)oh * 64 + ow;
#pragma unroll
    for (int oc = 0; oc < 64; ++oc)
        out[obase + (size_t)oc * 64 * 64] = __float2bfloat16(fmaxf(acc[oc], 0.f));
}

// ---------------------------------------------------------------------------
// conv2: bf16 [B,64,64,64] -> bf16 [B,128,32,32], stride 2 pad 1, ReLU
// thread = (b, oh, ow), all 128 oc in registers. block (32,8), grid (4, B)
// ---------------------------------------------------------------------------
__global__ __launch_bounds__(256, 2) void conv2_kernel(
    const __hip_bfloat16* __restrict__ in, const float* __restrict__ wt /*[576][128]*/,
    const float* __restrict__ bias, __hip_bfloat16* __restrict__ out) {
    const int ow = threadIdx.x;                      // 0..31
    const int oh = blockIdx.x * 8 + threadIdx.y;     // 0..31
    const int b  = blockIdx.y;
    float acc[128];
#pragma unroll
    for (int oc = 0; oc < 128; ++oc) acc[oc] = bias[oc];
    for (int c = 0; c < 64; ++c) {
        const __hip_bfloat16* bp = in + ((size_t)(b * 64 + c)) * 64 * 64;
#pragma unroll
        for (int kh = 0; kh < 3; ++kh) {
            int ih = oh * 2 - 1 + kh;
            bool vh = (unsigned)ih < 64u;
#pragma unroll
            for (int kw = 0; kw < 3; ++kw) {
                int iw = ow * 2 - 1 + kw;
                bool v = vh && ((unsigned)iw < 64u);
                float x = v ? __bfloat162float(bp[ih * 64 + iw]) : 0.f;
                const float* w = wt + (c * 9 + kh * 3 + kw) * 128;
#pragma unroll
                for (int oc = 0; oc < 128; ++oc) acc[oc] = fmaf(x, w[oc], acc[oc]);
            }
        }
    }
    size_t obase = ((size_t)b * 128) * 32 * 32 + (size_t)oh * 32 + ow;
#pragma unroll
    for (int oc = 0; oc < 128; ++oc)
        out[obase + (size_t)oc * 32 * 32] = __float2bfloat16(fmaxf(acc[oc], 0.f));
}

// ---------------------------------------------------------------------------
// conv3 + ReLU + fused global average pool: bf16 [B,128,32,32] -> fp32 v[B,256]
// block = 256 threads = full 16x16 output spatial of one image; 128-oc halves
// via blockIdx.x. Mean over spatial = block reduction (never writes conv3 out).
// ---------------------------------------------------------------------------
__global__ __launch_bounds__(256, 2) void conv3_pool_kernel(
    const __hip_bfloat16* __restrict__ in, const float* __restrict__ wt /*[1152][256]*/,
    const float* __restrict__ bias, float* __restrict__ v /*[B,256]*/) {
    const int tid = threadIdx.x;
    const int ow  = tid & 15, oh = tid >> 4;
    const int oc0 = blockIdx.x * 128;    // 0 or 128
    const int b   = blockIdx.y;
    float acc[128];
#pragma unroll
    for (int oc = 0; oc < 128; ++oc) acc[oc] = bias[oc0 + oc];
    for (int c = 0; c < 128; ++c) {
        const __hip_bfloat16* bp = in + ((size_t)(b * 128 + c)) * 32 * 32;
#pragma unroll
        for (int kh = 0; kh < 3; ++kh) {
            int ih = oh * 2 - 1 + kh;
            bool vh = (unsigned)ih < 32u;
#pragma unroll
            for (int kw = 0; kw < 3; ++kw) {
                int iw = ow * 2 - 1 + kw;
                bool vv = vh && ((unsigned)iw < 32u);
                float x = vv ? __bfloat162float(bp[ih * 32 + iw]) : 0.f;
                const float* w = wt + (c * 9 + kh * 3 + kw) * 256 + oc0;
#pragma unroll
                for (int oc = 0; oc < 128; ++oc) acc[oc] = fmaf(x, w[oc], acc[oc]);
            }
        }
    }
    // ReLU then mean over the 256 spatial positions (one per thread)
    __shared__ float red[4][128];
    const int lane = tid & 63, wid = tid >> 6;
#pragma unroll
    for (int oc = 0; oc < 128; ++oc) {
        float s = fmaxf(acc[oc], 0.f);
#pragma unroll
        for (int off = 32; off > 0; off >>= 1) s += __shfl_xor(s, off, 64);
        acc[oc] = s;
    }
    if (lane == 0) {
#pragma unroll
        for (int oc = 0; oc < 128; ++oc) red[wid][oc] = acc[oc];
    }
    __syncthreads();
    if (tid < 128) {
        float s = red[0][tid] + red[1][tid] + red[2][tid] + red[3][tid];
        v[(size_t)b * 256 + oc0 + tid] = s * (1.f / 256.f);
    }
}

// ---------------------------------------------------------------------------
// Entire post-pool tail, one block (256 threads) per sample:
// proprio MLP -> f1 -> f2 -> [f,e] -> g -> routed heads h1,h2,h3 -> out[B,4]
// ---------------------------------------------------------------------------
__global__ __launch_bounds__(256) void tail_kernel(
    const float* __restrict__ prop, const int* __restrict__ task_ids,
    const float* __restrict__ p1_w, const float* __restrict__ p1_b,
    const float* __restrict__ p2_w, const float* __restrict__ p2_b,
    const float* __restrict__ v,
    const float* __restrict__ f1_w, const float* __restrict__ f1_b,
    const float* __restrict__ f2_w, const float* __restrict__ f2_b,
    const float* __restrict__ task_emb,
    const float* __restrict__ g_w, const float* __restrict__ g_b,
    const float* __restrict__ h1_w, const float* __restrict__ h1_b,
    const float* __restrict__ h2_w, const float* __restrict__ h2_b,
    const float* __restrict__ h3_w, const float* __restrict__ h3_b,
    float* __restrict__ out) {
    const int b   = blockIdx.x;
    const int tid = threadIdx.x;
    const int t   = task_ids[b];
    __shared__ float sa[320];   // holds [v|p] then [f|e] then a1
    __shared__ float sb[288];   // holds f1-out then z then a2
    __shared__ float sph[64];

    sa[tid >= 256 ? 0 : tid] = 0.f;  // harmless init; real writes below
    if (tid < 256) sa[tid] = v[(size_t)b * 256 + tid];
    if (tid < 64) {
        float h = p1_b[tid];
        for (int k = 0; k < 7; ++k) h = fmaf(prop[b * 7 + k], p1_w[k * 64 + tid], h);
        sph[tid] = fmaxf(h, 0.f);
    }
    __syncthreads();
    if (tid < 64) {
        float h = p2_b[tid];
        for (int k = 0; k < 64; ++k) h = fmaf(sph[k], p2_w[k * 64 + tid], h);
        sa[256 + tid] = h;   // no ReLU on p
    }
    __syncthreads();
    // f1: 320 -> 256, ReLU
    {
        float a = f1_b[tid];
        for (int k = 0; k < 320; ++k) a = fmaf(sa[k], f1_w[k * 256 + tid], a);
        sb[tid] = fmaxf(a, 0.f);
    }
    __syncthreads();
    // f2: 256 -> 256, ReLU -> sa[0..255]; task embedding -> sa[256..287]
    {
        float a = f2_b[tid];
        for (int k = 0; k < 256; ++k) a = fmaf(sb[k], f2_w[k * 256 + tid], a);
        sa[tid] = fmaxf(a, 0.f);
    }
    if (tid < 32) sa[256 + tid] = task_emb[t * 32 + tid];
    __syncthreads();
    // g: 288 -> 256, ReLU (z)
    {
        float a = g_b[tid];
        for (int k = 0; k < 288; ++k) a = fmaf(sa[k], g_w[k * 256 + tid], a);
        sb[tid] = fmaxf(a, 0.f);
    }
    __syncthreads();
    // h1: 256 -> 128, ReLU
    if (tid < 128) {
        float a = h1_b[t * 128 + tid];
        for (int k = 0; k < 256; ++k)
            a = fmaf(sb[k], h1_w[((size_t)t * 256 + k) * 128 + tid], a);
        sa[tid] = fmaxf(a, 0.f);
    }
    __syncthreads();
    // h2: 128 -> 128, ReLU
    if (tid < 128) {
        float a = h2_b[t * 128 + tid];
        for (int k = 0; k < 128; ++k)
            a = fmaf(sa[k], h2_w[((size_t)t * 128 + k) * 128 + tid], a);
        sb[tid] = fmaxf(a, 0.f);
    }
    __syncthreads();
    // h3: 128 -> 4 (no ReLU)
    if (tid < 4) {
        float a = h3_b[t * 4 + tid];
        for (int k = 0; k < 128; ++k)
            a = fmaf(sb[k], h3_w[((size_t)t * 128 + k) * 4 + tid], a);
        out[b * 4 + tid] = a;
    }
}

// ---------------------------------------------------------------------------
extern "C" void kernel_launch(void* const* d_in, const int* in_sizes, int n_in,
                              void* d_out, int out_size, void* d_ws, size_t ws_size,
                              hipStream_t stream) {
    (void)in_sizes; (void)n_in; (void)out_size; (void)ws_size;
    const float* images   = (const float*)d_in[0];
    const float* prop     = (const float*)d_in[1];
    const int*   task_ids = (const int*)d_in[2];
    const float* c1_w = (const float*)d_in[3];
    const float* c1_b = (const float*)d_in[4];
    const float* c2_w = (const float*)d_in[5];
    const float* c2_b = (const float*)d_in[6];
    const float* c3_w = (const float*)d_in[7];
    const float* c3_b = (const float*)d_in[8];
    const float* p1_w = (const float*)d_in[9];
    const float* p1_b = (const float*)d_in[10];
    const float* p2_w = (const float*)d_in[11];
    const float* p2_b = (const float*)d_in[12];
    const float* f1_w = (const float*)d_in[13];
    const float* f1_b = (const float*)d_in[14];
    const float* f2_w = (const float*)d_in[15];
    const float* f2_b = (const float*)d_in[16];
    const float* temb = (const float*)d_in[17];
    const float* g_w  = (const float*)d_in[18];
    const float* g_b  = (const float*)d_in[19];
    const float* h1_w = (const float*)d_in[20];
    const float* h1_b = (const float*)d_in[21];
    const float* h2_w = (const float*)d_in[22];
    const float* h2_b = (const float*)d_in[23];
    const float* h3_w = (const float*)d_in[24];
    const float* h3_b = (const float*)d_in[25];
    float* out = (float*)d_out;

    // workspace layout (chunked over batch: CH=128 images -> ~102 MB total)
    const int B = 256, CH = 128;
    char* ws = (char*)d_ws;
    size_t off = 0;
    auto alloc = [&](size_t bytes) {
        void* p = ws + off;
        off += (bytes + 255) & ~(size_t)255;
        return p;
    };
    __hip_bfloat16* act1 = (__hip_bfloat16*)alloc((size_t)CH * 64 * 64 * 64 * 2);
    __hip_bfloat16* act2 = (__hip_bfloat16*)alloc((size_t)CH * 128 * 32 * 32 * 2);
    float* vbuf = (float*)alloc((size_t)B * 256 * 4);
    float* w1t  = (float*)alloc((size_t)1728 * 4);
    float* w2t  = (float*)alloc((size_t)73728 * 4);
    float* w3t  = (float*)alloc((size_t)294912 * 4);

    transpose_w_kernel<<<DIV_UP(1728, 256), 256, 0, stream>>>(c1_w, w1t, 64, 3);
    transpose_w_kernel<<<DIV_UP(73728, 256), 256, 0, stream>>>(c2_w, w2t, 128, 64);
    transpose_w_kernel<<<DIV_UP(294912, 256), 256, 0, stream>>>(c3_w, w3t, 256, 128);

    for (int c0 = 0; c0 < B; c0 += CH) {
        const float* img_c = images + (size_t)c0 * 3 * 128 * 128;
        conv1_kernel<<<dim3(16, CH), dim3(64, 4), 0, stream>>>(img_c, w1t, c1_b, act1);
        conv2_kernel<<<dim3(4, CH), dim3(32, 8), 0, stream>>>(act1, w2t, c2_b, act2);
        conv3_pool_kernel<<<dim3(2, CH), 256, 0, stream>>>(act2, w3t, c3_b,
                                                           vbuf + (size_t)c0 * 256);
    }
    tail_kernel<<<256, 256, 0, stream>>>(prop, task_ids, p1_w, p1_b, p2_w, p2_b,
                                         vbuf, f1_w, f1_b, f2_w, f2_b, temb,
                                         g_w, g_b, h1_w, h1_b, h2_w, h2_b,
                                         h3_w, h3_b, out);
}

// Round 2
// 639.562 us; speedup vs baseline: 12.4784x; 12.4784x over previous
//
#include <hip/hip_runtime.h>
#include <hip/hip_bf16.h>

#define DIV_UP(a,b) (((a)+(b)-1)/(b))

typedef __attribute__((ext_vector_type(8))) short short8;
typedef __attribute__((ext_vector_type(4))) float f32x4;

__device__ __forceinline__ void gld_lds16(const void* g, void* l) {
    __builtin_amdgcn_global_load_lds(
        (const __attribute__((address_space(1))) void*)g,
        (__attribute__((address_space(3))) void*)l, 16, 0, 0);
}

// ---------------------------------------------------------------------------
// conv1 weights OIHW [64,3,3,3] -> fp32 [27][64] (k-major for direct kernel)
// ---------------------------------------------------------------------------
__global__ void transpose_w1_kernel(const float* __restrict__ src,
                                    float* __restrict__ dst) {
    int t = blockIdx.x * blockDim.x + threadIdx.x;
    if (t >= 1728) return;
    int oc = t % 64;
    int r  = t / 64;        // r = c*9 + q
    int q  = r % 9;
    int c  = r / 9;
    dst[t] = src[(oc * 3 + c) * 9 + q];
}

// ---------------------------------------------------------------------------
// conv2/3 weights OIHW [O][C][9] fp32 -> bf16 [O][9*C], k = tap*C + c
// (n-major so GEMM B staging reads contiguous per-n K-slices)
// ---------------------------------------------------------------------------
__global__ void repack_w_kernel(const float* __restrict__ src,
                                __hip_bfloat16* __restrict__ dst, int O, int C) {
    int t = blockIdx.x * blockDim.x + threadIdx.x;
    if (t >= O * C * 9) return;
    int o   = t / (C * 9);
    int r   = t % (C * 9);
    int tap = r / C;
    int c   = r % C;
    dst[t] = __float2bfloat16(src[(o * C + c) * 9 + tap]);
}

// ---------------------------------------------------------------------------
// conv1: fp32 NCHW [CH,3,128,128] -> bf16 padded NHWC [CH,65,65,64], ReLU
// thread=(b,oh,ow), 64 oc in registers. block (64,4), grid (16, CH)
// ---------------------------------------------------------------------------
__global__ __launch_bounds__(256, 4) void conv1_kernel(
    const float* __restrict__ in, const float* __restrict__ wt /*[27][64]*/,
    const float* __restrict__ bias, __hip_bfloat16* __restrict__ out) {
    const int ow = threadIdx.x;                      // 0..63
    const int oh = blockIdx.x * 4 + threadIdx.y;     // 0..63
    const int b  = blockIdx.y;
    float acc[64];
#pragma unroll
    for (int oc = 0; oc < 64; ++oc) acc[oc] = bias[oc];
    for (int c = 0; c < 3; ++c) {
        const float* bp = in + ((size_t)(b * 3 + c)) * 128 * 128;
#pragma unroll
        for (int kh = 0; kh < 3; ++kh) {
            int ih = oh * 2 - 1 + kh;
            bool vh = (unsigned)ih < 128u;
#pragma unroll
            for (int kw = 0; kw < 3; ++kw) {
                int iw = ow * 2 - 1 + kw;
                bool v = vh && ((unsigned)iw < 128u);
                float x = v ? bp[ih * 128 + iw] : 0.f;
                const float* w = wt + (c * 9 + kh * 3 + kw) * 64;
#pragma unroll
                for (int oc = 0; oc < 64; ++oc) acc[oc] = fmaf(x, w[oc], acc[oc]);
            }
        }
    }
    // padded NHWC store: 8 groups of 8 bf16 -> uint4 (avoids a 2nd 64-reg array)
    size_t obase = (((size_t)b * 65 + oh + 1) * 65 + (ow + 1)) * 64;
    uint4* op = (uint4*)(out + obase);
#pragma unroll
    for (int q = 0; q < 8; ++q) {
        union { uint4 u4; __hip_bfloat16 h[8]; } pk;
#pragma unroll
        for (int e = 0; e < 8; ++e)
            pk.h[e] = __float2bfloat16(fmaxf(acc[q * 8 + e], 0.f));
        op[q] = pk.u4;
    }
}

// ---------------------------------------------------------------------------
// Implicit-GEMM conv, bf16 MFMA 16x16x32, 128x128 C-tile, BK=64 (one tap or
// half-tap). A = im2col rows (b,oh,ow) from padded NHWC act; B = [N][K] bf16
// weights. Both staged via global_load_lds(16B) into seg-major LDS:
//   LDS chunk ci = seg*128 + row  (seg = k/8 within BK, row = m or n 0..127)
// so staging is lane-contiguous AND frag ds_read_b128 hits 4x256B regions.
// ---------------------------------------------------------------------------
template<int CIN, int LOGSP, int LOGOW, int IPH, int IPW,
         int NOUT, int OPH, int OPW, int OPAD>
__global__ __launch_bounds__(256, 2) void conv_gemm_kernel(
    const __hip_bfloat16* __restrict__ act,  // padded NHWC input
    const __hip_bfloat16* __restrict__ wtB,  // [NOUT][9*CIN]
    const float* __restrict__ bias,
    __hip_bfloat16* __restrict__ out) {
    constexpr int KTOT   = CIN * 9;
    constexpr int KSTEPS = KTOT / 64;
    const int tid  = threadIdx.x;
    const int lane = tid & 63;
    const int w    = tid >> 6;           // wave 0..3
    const int l15  = lane & 15;
    const int quad = lane >> 4;
    const int Mt   = blockIdx.x;
    const int N0   = blockIdx.y * 128;

    __shared__ uint4 As4[1024];          // 16 KB: A[128 m][64 k]
    __shared__ uint4 Bs4[1024];          // 16 KB: B[128 n][64 k] (k fast, seg-major)

    // staging addresses: issue gi = w*4+i covers chunks [gi*64, gi*64+64)
    // chunk ci -> seg = ci>>7, row = ci&127 ; lane l -> ci = gi*64 + l
    const __hip_bfloat16* aBase[4];
    const __hip_bfloat16* bBase[4];
#pragma unroll
    for (int i = 0; i < 4; ++i) {
        int gi = w * 4 + i;
        int s  = gi >> 1;                    // k-seg 0..7 (8 bf16 each)
        int r  = ((gi & 1) << 6) + lane;     // row 0..127
        int m  = (Mt << 7) + r;
        int b  = m >> LOGSP;
        int rr = m & ((1 << LOGSP) - 1);
        int oh = rr >> LOGOW;
        int ow = rr & ((1 << LOGOW) - 1);
        aBase[i] = act + ((size_t)(b * IPH + oh * 2) * IPW + ow * 2) * CIN + s * 8;
        bBase[i] = wtB + (size_t)(N0 + r) * KTOT + s * 8;
    }

    f32x4 acc[4][4];
#pragma unroll
    for (int i = 0; i < 4; ++i)
#pragma unroll
        for (int j = 0; j < 4; ++j) acc[i][j] = (f32x4){0.f, 0.f, 0.f, 0.f};

    const int wm = (w & 1) << 6;    // wave row offset in C-tile
    const int wn = (w >> 1) << 6;   // wave col offset

    for (int t = 0; t < KSTEPS; ++t) {
        int tap, c0;
        if (CIN == 64) { tap = t; c0 = 0; }
        else           { tap = t >> 1; c0 = (t & 1) << 6; }
        int kh = tap / 3, kw = tap - kh * 3;
        int aoff = (kh * IPW + kw) * CIN + c0;
        __syncthreads();   // previous compute's LDS reads done
#pragma unroll
        for (int i = 0; i < 4; ++i) {
            int gi = w * 4 + i;
            gld_lds16(aBase[i] + aoff, As4 + gi * 64);
            gld_lds16(bBase[i] + t * 64, Bs4 + gi * 64);
        }
        __syncthreads();   // vmcnt(0) drain before frag reads
#pragma unroll
        for (int ks = 0; ks < 2; ++ks) {
            short8 af[4], bf[4];
#pragma unroll
            for (int i = 0; i < 4; ++i) {
                int sF = ks * 4 + quad;   // k-seg = (ks*32 + quad*8)/8
                af[i] = __builtin_bit_cast(short8, As4[sF * 128 + wm + i * 16 + l15]);
                bf[i] = __builtin_bit_cast(short8, Bs4[sF * 128 + wn + i * 16 + l15]);
            }
#pragma unroll
            for (int i = 0; i < 4; ++i)
#pragma unroll
                for (int j = 0; j < 4; ++j)
                    acc[i][j] = __builtin_amdgcn_mfma_f32_16x16x32_bf16(
                        af[i], bf[j], acc[i][j], 0, 0, 0);
        }
    }

    // epilogue: bias + ReLU + bf16, write NHWC (optionally padded)
    // D layout: row m = quad*4 + r, col n = l15  [m89-verified]
#pragma unroll
    for (int j = 0; j < 4; ++j) {
        int n = N0 + wn + j * 16 + l15;
        float bv = bias[n];
#pragma unroll
        for (int i = 0; i < 4; ++i) {
#pragma unroll
            for (int r = 0; r < 4; ++r) {
                int m  = (Mt << 7) + wm + i * 16 + quad * 4 + r;
                int b  = m >> LOGSP;
                int rr = m & ((1 << LOGSP) - 1);
                int oh = rr >> LOGOW;
                int ow = rr & ((1 << LOGOW) - 1);
                float vo = fmaxf(acc[i][j][r] + bv, 0.f);
                out[((size_t)(b * OPH + oh + OPAD) * OPW + ow + OPAD) * NOUT + n] =
                    __float2bfloat16(vo);
            }
        }
    }
}

// ---------------------------------------------------------------------------
// global average pool over 256 spatial: bf16 [CH,256,256] -> fp32 v[CH,256]
// ---------------------------------------------------------------------------
__global__ __launch_bounds__(256) void pool_kernel(
    const __hip_bfloat16* __restrict__ act3, float* __restrict__ v) {
    int b = blockIdx.x, c = threadIdx.x;
    float s = 0.f;
    for (int sp = 0; sp < 256; ++sp)
        s += __bfloat162float(act3[((size_t)b * 256 + sp) * 256 + c]);
    v[(size_t)b * 256 + c] = s * (1.f / 256.f);
}

// ---------------------------------------------------------------------------
// post-pool tail, one block per sample (unchanged from round 1 — it passed)
// ---------------------------------------------------------------------------
__global__ __launch_bounds__(256) void tail_kernel(
    const float* __restrict__ prop, const int* __restrict__ task_ids,
    const float* __restrict__ p1_w, const float* __restrict__ p1_b,
    const float* __restrict__ p2_w, const float* __restrict__ p2_b,
    const float* __restrict__ v,
    const float* __restrict__ f1_w, const float* __restrict__ f1_b,
    const float* __restrict__ f2_w, const float* __restrict__ f2_b,
    const float* __restrict__ task_emb,
    const float* __restrict__ g_w, const float* __restrict__ g_b,
    const float* __restrict__ h1_w, const float* __restrict__ h1_b,
    const float* __restrict__ h2_w, const float* __restrict__ h2_b,
    const float* __restrict__ h3_w, const float* __restrict__ h3_b,
    float* __restrict__ out) {
    const int b   = blockIdx.x;
    const int tid = threadIdx.x;
    const int t   = task_ids[b];
    __shared__ float sa[320];
    __shared__ float sb[288];
    __shared__ float sph[64];

    if (tid < 256) sa[tid] = v[(size_t)b * 256 + tid];
    if (tid < 64) {
        float h = p1_b[tid];
        for (int k = 0; k < 7; ++k) h = fmaf(prop[b * 7 + k], p1_w[k * 64 + tid], h);
        sph[tid] = fmaxf(h, 0.f);
    }
    __syncthreads();
    if (tid < 64) {
        float h = p2_b[tid];
        for (int k = 0; k < 64; ++k) h = fmaf(sph[k], p2_w[k * 64 + tid], h);
        sa[256 + tid] = h;
    }
    __syncthreads();
    {
        float a = f1_b[tid];
        for (int k = 0; k < 320; ++k) a = fmaf(sa[k], f1_w[k * 256 + tid], a);
        sb[tid] = fmaxf(a, 0.f);
    }
    __syncthreads();
    {
        float a = f2_b[tid];
        for (int k = 0; k < 256; ++k) a = fmaf(sb[k], f2_w[k * 256 + tid], a);
        sa[tid] = fmaxf(a, 0.f);
    }
    if (tid < 32) sa[256 + tid] = task_emb[t * 32 + tid];
    __syncthreads();
    {
        float a = g_b[tid];
        for (int k = 0; k < 288; ++k) a = fmaf(sa[k], g_w[k * 256 + tid], a);
        sb[tid] = fmaxf(a, 0.f);
    }
    __syncthreads();
    if (tid < 128) {
        float a = h1_b[t * 128 + tid];
        for (int k = 0; k < 256; ++k)
            a = fmaf(sb[k], h1_w[((size_t)t * 256 + k) * 128 + tid], a);
        sa[tid] = fmaxf(a, 0.f);
    }
    __syncthreads();
    if (tid < 128) {
        float a = h2_b[t * 128 + tid];
        for (int k = 0; k < 128; ++k)
            a = fmaf(sa[k], h2_w[((size_t)t * 128 + k) * 128 + tid], a);
        sb[tid] = fmaxf(a, 0.f);
    }
    __syncthreads();
    if (tid < 4) {
        float a = h3_b[t * 4 + tid];
        for (int k = 0; k < 128; ++k)
            a = fmaf(sb[k], h3_w[((size_t)t * 128 + k) * 4 + tid], a);
        out[b * 4 + tid] = a;
    }
}

// ---------------------------------------------------------------------------
extern "C" void kernel_launch(void* const* d_in, const int* in_sizes, int n_in,
                              void* d_out, int out_size, void* d_ws, size_t ws_size,
                              hipStream_t stream) {
    (void)in_sizes; (void)n_in; (void)out_size; (void)ws_size;
    const float* images   = (const float*)d_in[0];
    const float* prop     = (const float*)d_in[1];
    const int*   task_ids = (const int*)d_in[2];
    const float* c1_w = (const float*)d_in[3];
    const float* c1_b = (const float*)d_in[4];
    const float* c2_w = (const float*)d_in[5];
    const float* c2_b = (const float*)d_in[6];
    const float* c3_w = (const float*)d_in[7];
    const float* c3_b = (const float*)d_in[8];
    const float* p1_w = (const float*)d_in[9];
    const float* p1_b = (const float*)d_in[10];
    const float* p2_w = (const float*)d_in[11];
    const float* p2_b = (const float*)d_in[12];
    const float* f1_w = (const float*)d_in[13];
    const float* f1_b = (const float*)d_in[14];
    const float* f2_w = (const float*)d_in[15];
    const float* f2_b = (const float*)d_in[16];
    const float* temb = (const float*)d_in[17];
    const float* g_w  = (const float*)d_in[18];
    const float* g_b  = (const float*)d_in[19];
    const float* h1_w = (const float*)d_in[20];
    const float* h1_b = (const float*)d_in[21];
    const float* h2_w = (const float*)d_in[22];
    const float* h2_b = (const float*)d_in[23];
    const float* h3_w = (const float*)d_in[24];
    const float* h3_b = (const float*)d_in[25];
    float* out = (float*)d_out;

    const int B = 256, CH = 64;   // 4 chunks; ws ~62 MB
    char* ws = (char*)d_ws;
    size_t off = 0;
    auto alloc = [&](size_t bytes) {
        void* p = ws + off;
        off += (bytes + 255) & ~(size_t)255;
        return p;
    };
    const size_t act1_bytes = (size_t)CH * 65 * 65 * 64 * 2;   // 34.6 MB
    const size_t act2_bytes = (size_t)CH * 33 * 33 * 128 * 2;  // 17.8 MB
    __hip_bfloat16* act1 = (__hip_bfloat16*)alloc(act1_bytes);
    __hip_bfloat16* act2 = (__hip_bfloat16*)alloc(act2_bytes);
    __hip_bfloat16* act3 = (__hip_bfloat16*)alloc((size_t)CH * 256 * 256 * 2);
    float*          vbuf = (float*)alloc((size_t)B * 256 * 4);
    float*          w1t  = (float*)alloc((size_t)1728 * 4);
    __hip_bfloat16* w2t  = (__hip_bfloat16*)alloc((size_t)73728 * 2);
    __hip_bfloat16* w3t  = (__hip_bfloat16*)alloc((size_t)294912 * 2);

    // zero act1/act2 once: establishes the 1-pixel halo; interiors are
    // overwritten every chunk, halo stays zero.
    hipMemsetAsync(act1, 0, act1_bytes, stream);
    hipMemsetAsync(act2, 0, act2_bytes, stream);

    transpose_w1_kernel<<<DIV_UP(1728, 256), 256, 0, stream>>>(c1_w, w1t);
    repack_w_kernel<<<DIV_UP(73728, 256), 256, 0, stream>>>(c2_w, w2t, 128, 64);
    repack_w_kernel<<<DIV_UP(294912, 256), 256, 0, stream>>>(c3_w, w3t, 256, 128);

    for (int c0 = 0; c0 < B; c0 += CH) {
        const float* img_c = images + (size_t)c0 * 3 * 128 * 128;
        conv1_kernel<<<dim3(16, CH), dim3(64, 4), 0, stream>>>(img_c, w1t, c1_b, act1);
        // conv2: M = CH*32*32 = 65536 -> 512 M-tiles, N=128 -> 1 N-tile
        conv_gemm_kernel<64, 10, 5, 65, 65, 128, 33, 33, 1>
            <<<dim3(512, 1), 256, 0, stream>>>(act1, w2t, c2_b, act2);
        // conv3: M = CH*16*16 = 16384 -> 128 M-tiles, N=256 -> 2 N-tiles
        conv_gemm_kernel<128, 8, 4, 33, 33, 256, 16, 16, 0>
            <<<dim3(128, 2), 256, 0, stream>>>(act2, w3t, c3_b, act3);
        pool_kernel<<<CH, 256, 0, stream>>>(act3, vbuf + (size_t)c0 * 256);
    }
    tail_kernel<<<256, 256, 0, stream>>>(prop, task_ids, p1_w, p1_b, p2_w, p2_b,
                                         vbuf, f1_w, f1_b, f2_w, f2_b, temb,
                                         g_w, g_b, h1_w, h1_b, h2_w, h2_b,
                                         h3_w, h3_b, out);
}

// Round 4
// 544.448 us; speedup vs baseline: 14.6584x; 1.1747x over previous
//
#include <hip/hip_runtime.h>
#include <hip/hip_bf16.h>

#define DIV_UP(a,b) (((a)+(b)-1)/(b))

typedef __attribute__((ext_vector_type(8))) short short8;
typedef __attribute__((ext_vector_type(4))) float f32x4;

__device__ __forceinline__ void gld_lds16(const void* g, void* l) {
    __builtin_amdgcn_global_load_lds(
        (const __attribute__((address_space(1))) void*)g,
        (__attribute__((address_space(3))) void*)l, 16, 0, 0);
}

__device__ __forceinline__ ushort bf16_bits(float x) {
    return __builtin_bit_cast(ushort, __float2bfloat16(x));
}

// ---------------------------------------------------------------------------
// conv1 weights OIHW [64,3,3,3] -> fp32 [27][64]
// ---------------------------------------------------------------------------
__global__ void transpose_w1_kernel(const float* __restrict__ src,
                                    float* __restrict__ dst) {
    int t = blockIdx.x * blockDim.x + threadIdx.x;
    if (t >= 1728) return;
    int oc = t % 64;
    int r  = t / 64;
    int q  = r % 9;
    int c  = r / 9;
    dst[t] = src[(oc * 3 + c) * 9 + q];
}

// ---------------------------------------------------------------------------
// conv2/3 weights OIHW [O][C][9] fp32 -> bf16 [O][9*C], k = tap*C + c
// ---------------------------------------------------------------------------
__global__ void repack_w_kernel(const float* __restrict__ src,
                                __hip_bfloat16* __restrict__ dst, int O, int C) {
    int t = blockIdx.x * blockDim.x + threadIdx.x;
    if (t >= O * C * 9) return;
    int o   = t / (C * 9);
    int r   = t % (C * 9);
    int tap = r / C;
    int c   = r % C;
    dst[t] = __float2bfloat16(src[(o * C + c) * 9 + tap]);
}

// ---------------------------------------------------------------------------
// conv1: fp32 NCHW [64,3,128,128] -> bf16 padded NHWC [64,65,65,64], ReLU
// ---------------------------------------------------------------------------
__global__ __launch_bounds__(256, 4) void conv1_kernel(
    const float* __restrict__ in, const float* __restrict__ wt,
    const float* __restrict__ bias, __hip_bfloat16* __restrict__ out) {
    const int ow = threadIdx.x;
    const int oh = blockIdx.x * 4 + threadIdx.y;
    const int b  = blockIdx.y;
    float acc[64];
#pragma unroll
    for (int oc = 0; oc < 64; ++oc) acc[oc] = bias[oc];
    for (int c = 0; c < 3; ++c) {
        const float* bp = in + ((size_t)(b * 3 + c)) * 128 * 128;
#pragma unroll
        for (int kh = 0; kh < 3; ++kh) {
            int ih = oh * 2 - 1 + kh;
            bool vh = (unsigned)ih < 128u;
#pragma unroll
            for (int kw = 0; kw < 3; ++kw) {
                int iw = ow * 2 - 1 + kw;
                bool v = vh && ((unsigned)iw < 128u);
                float x = v ? bp[ih * 128 + iw] : 0.f;
                const float* w = wt + (c * 9 + kh * 3 + kw) * 64;
#pragma unroll
                for (int oc = 0; oc < 64; ++oc) acc[oc] = fmaf(x, w[oc], acc[oc]);
            }
        }
    }
    size_t obase = (((size_t)b * 65 + oh + 1) * 65 + (ow + 1)) * 64;
    uint4* op = (uint4*)(out + obase);
#pragma unroll
    for (int q = 0; q < 8; ++q) {
        union { uint4 u4; ushort h[8]; } pk;
#pragma unroll
        for (int e = 0; e < 8; ++e)
            pk.h[e] = bf16_bits(fmaxf(acc[q * 8 + e], 0.f));
        op[q] = pk.u4;
    }
}

// ---------------------------------------------------------------------------
// conv2 implicit-GEMM: bf16 [64,65,65,64] -> bf16 padded [64,33,33,128], ReLU
// 128x128 tile, BK=64 (one tap). Epilogue staged through LDS (stride 132
// ushorts) then 8B coalesced stores.
// ---------------------------------------------------------------------------
__global__ __launch_bounds__(256, 2) void conv2_gemm_kernel(
    const __hip_bfloat16* __restrict__ act,
    const __hip_bfloat16* __restrict__ wtB,   // [128][576]
    const float* __restrict__ bias,
    __hip_bfloat16* __restrict__ out) {
    constexpr int CIN = 64, KTOT = 576, KSTEPS = 9;
    constexpr int IPW = 65, IPH = 65;
    const int tid  = threadIdx.x;
    const int lane = tid & 63;
    const int w    = tid >> 6;
    const int l15  = lane & 15;
    const int quad = lane >> 4;
    const int Mt   = blockIdx.x;

    __shared__ __align__(16) char smem[33792];
    uint4*  As4 = (uint4*)smem;
    uint4*  Bs4 = As4 + 1024;
    ushort* Cs  = (ushort*)smem;

    const __hip_bfloat16* aBase[4];
    const __hip_bfloat16* bBase[4];
#pragma unroll
    for (int i = 0; i < 4; ++i) {
        int gi = w * 4 + i;
        int s  = gi >> 1;
        int r  = ((gi & 1) << 6) + lane;
        int m  = (Mt << 7) + r;
        int b  = m >> 10;
        int rr = m & 1023;
        int oh = rr >> 5;
        int ow = rr & 31;
        aBase[i] = act + ((size_t)(b * IPH + oh * 2) * IPW + ow * 2) * CIN + s * 8;
        bBase[i] = wtB + (size_t)r * KTOT + s * 8;
    }

    f32x4 acc[4][4];
#pragma unroll
    for (int i = 0; i < 4; ++i)
#pragma unroll
        for (int j = 0; j < 4; ++j) acc[i][j] = (f32x4){0.f, 0.f, 0.f, 0.f};

    const int wm = (w & 1) << 6;
    const int wn = (w >> 1) << 6;

    for (int t = 0; t < KSTEPS; ++t) {
        int kh = t / 3, kw = t - kh * 3;
        int aoff = (kh * IPW + kw) * CIN;
        __syncthreads();
#pragma unroll
        for (int i = 0; i < 4; ++i) {
            int gi = w * 4 + i;
            gld_lds16(aBase[i] + aoff, As4 + gi * 64);
            gld_lds16(bBase[i] + t * 64, Bs4 + gi * 64);
        }
        __syncthreads();
#pragma unroll
        for (int ks = 0; ks < 2; ++ks) {
            short8 af[4], bf[4];
#pragma unroll
            for (int i = 0; i < 4; ++i) {
                int sF = ks * 4 + quad;
                af[i] = __builtin_bit_cast(short8, As4[sF * 128 + wm + i * 16 + l15]);
                bf[i] = __builtin_bit_cast(short8, Bs4[sF * 128 + wn + i * 16 + l15]);
            }
#pragma unroll
            for (int i = 0; i < 4; ++i)
#pragma unroll
                for (int j = 0; j < 4; ++j)
                    acc[i][j] = __builtin_amdgcn_mfma_f32_16x16x32_bf16(
                        af[i], bf[j], acc[i][j], 0, 0, 0);
        }
    }

    // epilogue: bias+ReLU -> bf16 tile in LDS -> coalesced 8B stores
    __syncthreads();
#pragma unroll
    for (int j = 0; j < 4; ++j) {
        int n = wn + j * 16 + l15;
        float bv = bias[n];
#pragma unroll
        for (int i = 0; i < 4; ++i)
#pragma unroll
            for (int r = 0; r < 4; ++r) {
                int ml = wm + i * 16 + quad * 4 + r;
                Cs[ml * 132 + n] = bf16_bits(fmaxf(acc[i][j][r] + bv, 0.f));
            }
    }
    __syncthreads();
#pragma unroll
    for (int q = 0; q < 16; ++q) {
        int c   = tid + 256 * q;      // chunk of 4 ushorts (8B)
        int row = c >> 5;
        int off = c & 31;
        uint2 val = *(const uint2*)(Cs + row * 132 + off * 4);
        int m  = (Mt << 7) + row;
        int b  = m >> 10;
        int rr = m & 1023;
        int oh = rr >> 5;
        int ow = rr & 31;
        size_t pix = ((size_t)(b * 33 + oh + 1) * 33 + (ow + 1));
        *(uint2*)(out + pix * 128 + off * 4) = val;
    }
}

// ---------------------------------------------------------------------------
// conv3 implicit-GEMM + fused global-avg-pool: bf16 [128,33,33,128] ->
// fp32 v[128,256] via atomicAdd. Block = 128 spatial (half image) x 128 ch.
// ---------------------------------------------------------------------------
__global__ __launch_bounds__(256, 2) void conv3_gemm_pool_kernel(
    const __hip_bfloat16* __restrict__ act,
    const __hip_bfloat16* __restrict__ wtB,   // [256][1152]
    const float* __restrict__ bias,
    float* __restrict__ v /* [128,256], pre-zeroed */) {
    constexpr int CIN = 128, KTOT = 1152, KSTEPS = 18;
    constexpr int IPW = 33, IPH = 33;
    const int tid  = threadIdx.x;
    const int lane = tid & 63;
    const int w    = tid >> 6;
    const int l15  = lane & 15;
    const int quad = lane >> 4;
    const int Mt   = blockIdx.x;
    const int N0   = blockIdx.y * 128;

    __shared__ uint4 As4[1024];
    __shared__ uint4 Bs4[1024];
    __shared__ float sred[128][2];

    const __hip_bfloat16* aBase[4];
    const __hip_bfloat16* bBase[4];
#pragma unroll
    for (int i = 0; i < 4; ++i) {
        int gi = w * 4 + i;
        int s  = gi >> 1;
        int r  = ((gi & 1) << 6) + lane;
        int m  = (Mt << 7) + r;
        int b  = m >> 8;
        int rr = m & 255;
        int oh = rr >> 4;
        int ow = rr & 15;
        aBase[i] = act + ((size_t)(b * IPH + oh * 2) * IPW + ow * 2) * CIN + s * 8;
        bBase[i] = wtB + (size_t)(N0 + r) * KTOT + s * 8;
    }

    f32x4 acc[4][4];
#pragma unroll
    for (int i = 0; i < 4; ++i)
#pragma unroll
        for (int j = 0; j < 4; ++j) acc[i][j] = (f32x4){0.f, 0.f, 0.f, 0.f};

    const int wm = (w & 1) << 6;
    const int wn = (w >> 1) << 6;

    for (int t = 0; t < KSTEPS; ++t) {
        int tap = t >> 1, c0 = (t & 1) << 6;
        int kh = tap / 3, kw = tap - kh * 3;
        int aoff = (kh * IPW + kw) * CIN + c0;
        __syncthreads();
#pragma unroll
        for (int i = 0; i < 4; ++i) {
            int gi = w * 4 + i;
            gld_lds16(aBase[i] + aoff, As4 + gi * 64);
            gld_lds16(bBase[i] + t * 64, Bs4 + gi * 64);
        }
        __syncthreads();
#pragma unroll
        for (int ks = 0; ks < 2; ++ks) {
            short8 af[4], bf[4];
#pragma unroll
            for (int i = 0; i < 4; ++i) {
                int sF = ks * 4 + quad;
                af[i] = __builtin_bit_cast(short8, As4[sF * 128 + wm + i * 16 + l15]);
                bf[i] = __builtin_bit_cast(short8, Bs4[sF * 128 + wn + i * 16 + l15]);
            }
#pragma unroll
            for (int i = 0; i < 4; ++i)
#pragma unroll
                for (int j = 0; j < 4; ++j)
                    acc[i][j] = __builtin_amdgcn_mfma_f32_16x16x32_bf16(
                        af[i], bf[j], acc[i][j], 0, 0, 0);
        }
    }

    // fused pool: bias+ReLU per element, sum over this block's 128 spatial
    float s4[4];
#pragma unroll
    for (int j = 0; j < 4; ++j) {
        float bv = bias[N0 + wn + j * 16 + l15];
        float s = 0.f;
#pragma unroll
        for (int i = 0; i < 4; ++i)
#pragma unroll
            for (int r = 0; r < 4; ++r)
                s += fmaxf(acc[i][j][r] + bv, 0.f);
        s += __shfl_xor(s, 16, 64);   // reduce across quads (same l15)
        s += __shfl_xor(s, 32, 64);
        s4[j] = s;
    }
    if (quad == 0) {
#pragma unroll
        for (int j = 0; j < 4; ++j) sred[wn + j * 16 + l15][w & 1] = s4[j];
    }
    __syncthreads();
    if (tid < 128) {
        float val = (sred[tid][0] + sred[tid][1]) * (1.f / 256.f);
        int bimg = Mt >> 1;   // 2 m-tiles per image (256 spatial)
        atomicAdd(v + (size_t)bimg * 256 + N0 + tid, val);
    }
}

// ---------------------------------------------------------------------------
// Tail: one block (256 thr) per sample. Each GEMV stage splits K across
// threads with float4 weight loads, LDS partial reduce.
// ---------------------------------------------------------------------------
template<int N, int K, int S, bool RELU>
__device__ __forceinline__ void gemv_stage(const float* __restrict__ w,
                                           const float* __restrict__ bias,
                                           const float* in, float* outv,
                                           float4* red4, int tid) {
    constexpr int G = N / 4;        // float4 output groups
    constexpr int CHK = K / S;
    static_assert(G * S == 256 && CHK * S == K, "stage shape");
    const int g = tid % G, s = tid / G;
    const float4* wp = (const float4*)w;
    float4 a; a.x = a.y = a.z = a.w = 0.f;
    const int k0 = s * CHK;
#pragma unroll 8
    for (int i = 0; i < CHK; ++i) {
        float x = in[k0 + i];
        float4 wv = wp[(size_t)(k0 + i) * G + g];
        a.x = fmaf(x, wv.x, a.x);
        a.y = fmaf(x, wv.y, a.y);
        a.z = fmaf(x, wv.z, a.z);
        a.w = fmaf(x, wv.w, a.w);
    }
    red4[tid] = a;
    __syncthreads();
    if (tid < N) {
        int gg = tid >> 2, e = tid & 3;
        float vv = bias[tid];
#pragma unroll
        for (int ss = 0; ss < S; ++ss) {
            const float* rp = (const float*)(red4 + ss * G + gg);
            vv += rp[e];
        }
        if (RELU) vv = fmaxf(vv, 0.f);
        outv[tid] = vv;
    }
    __syncthreads();
}

__global__ __launch_bounds__(256) void tail_kernel(
    const float* __restrict__ prop, const int* __restrict__ task_ids,
    const float* __restrict__ p1_w, const float* __restrict__ p1_b,
    const float* __restrict__ p2_w, const float* __restrict__ p2_b,
    const float* __restrict__ v,
    const float* __restrict__ f1_w, const float* __restrict__ f1_b,
    const float* __restrict__ f2_w, const float* __restrict__ f2_b,
    const float* __restrict__ task_emb,
    const float* __restrict__ g_w, const float* __restrict__ g_b,
    const float* __restrict__ h1_w, const float* __restrict__ h1_b,
    const float* __restrict__ h2_w, const float* __restrict__ h2_b,
    const float* __restrict__ h3_w, const float* __restrict__ h3_b,
    float* __restrict__ out) {
    const int b   = blockIdx.x;
    const int tid = threadIdx.x;
    const int t   = task_ids[b];
    __shared__ float sa[320];
    __shared__ float sb[288];
    __shared__ float sph[64];
    __shared__ float4 red4[256];

    sa[tid] = (tid < 256) ? v[(size_t)b * 256 + tid] : 0.f;
    if (tid < 64) {
        float h = p1_b[tid];
#pragma unroll
        for (int k = 0; k < 7; ++k) h = fmaf(prop[b * 7 + k], p1_w[k * 64 + tid], h);
        sph[tid] = fmaxf(h, 0.f);
    }
    __syncthreads();
    gemv_stage<64, 64, 16, false>(p2_w, p2_b, sph, sa + 256, red4, tid);  // p
    gemv_stage<256, 320, 4, true>(f1_w, f1_b, sa, sb, red4, tid);         // f1
    gemv_stage<256, 256, 4, true>(f2_w, f2_b, sb, sa, red4, tid);         // f2
    if (tid < 32) sa[256 + tid] = task_emb[t * 32 + tid];
    __syncthreads();
    gemv_stage<256, 288, 4, true>(g_w, g_b, sa, sb, red4, tid);           // z
    gemv_stage<128, 256, 8, true>(h1_w + (size_t)t * 32768, h1_b + t * 128,
                                  sb, sa, red4, tid);                     // a1
    gemv_stage<128, 128, 8, true>(h2_w + (size_t)t * 16384, h2_b + t * 128,
                                  sa, sb, red4, tid);                     // a2
    // h3: 128 -> 4
    if (tid < 128) {
        float4 wv = ((const float4*)(h3_w + (size_t)t * 512))[tid];
        float x = sb[tid];
        float r0 = x * wv.x, r1 = x * wv.y, r2 = x * wv.z, r3 = x * wv.w;
#pragma unroll
        for (int off = 1; off < 64; off <<= 1) {
            r0 += __shfl_xor(r0, off, 64);
            r1 += __shfl_xor(r1, off, 64);
            r2 += __shfl_xor(r2, off, 64);
            r3 += __shfl_xor(r3, off, 64);
        }
        if ((tid & 63) == 0) {
            float4 rv; rv.x = r0; rv.y = r1; rv.z = r2; rv.w = r3;
            red4[tid >> 6] = rv;
        }
    }
    __syncthreads();
    if (tid < 4) {
        const float* ra = (const float*)(red4 + 0);
        const float* rb = (const float*)(red4 + 1);
        out[b * 4 + tid] = ra[tid] + rb[tid] + h3_b[t * 4 + tid];
    }
}

// ---------------------------------------------------------------------------
extern "C" void kernel_launch(void* const* d_in, const int* in_sizes, int n_in,
                              void* d_out, int out_size, void* d_ws, size_t ws_size,
                              hipStream_t stream) {
    (void)in_sizes; (void)n_in; (void)out_size; (void)ws_size;
    const float* images   = (const float*)d_in[0];
    const float* prop     = (const float*)d_in[1];
    const int*   task_ids = (const int*)d_in[2];
    const float* c1_w = (const float*)d_in[3];
    const float* c1_b = (const float*)d_in[4];
    const float* c2_w = (const float*)d_in[5];
    const float* c2_b = (const float*)d_in[6];
    const float* c3_w = (const float*)d_in[7];
    const float* c3_b = (const float*)d_in[8];
    const float* p1_w = (const float*)d_in[9];
    const float* p1_b = (const float*)d_in[10];
    const float* p2_w = (const float*)d_in[11];
    const float* p2_b = (const float*)d_in[12];
    const float* f1_w = (const float*)d_in[13];
    const float* f1_b = (const float*)d_in[14];
    const float* f2_w = (const float*)d_in[15];
    const float* f2_b = (const float*)d_in[16];
    const float* temb = (const float*)d_in[17];
    const float* g_w  = (const float*)d_in[18];
    const float* g_b  = (const float*)d_in[19];
    const float* h1_w = (const float*)d_in[20];
    const float* h1_b = (const float*)d_in[21];
    const float* h2_w = (const float*)d_in[22];
    const float* h2_b = (const float*)d_in[23];
    const float* h3_w = (const float*)d_in[24];
    const float* h3_b = (const float*)d_in[25];
    float* out = (float*)d_out;

    char* ws = (char*)d_ws;
    size_t off = 0;
    auto alloc = [&](size_t bytes) {
        void* p = ws + off;
        off += (bytes + 255) & ~(size_t)255;
        return p;
    };
    const size_t act1_bytes = (size_t)64 * 65 * 65 * 64 * 2;    // 34.6 MB (64 imgs)
    const size_t act2_bytes = (size_t)128 * 33 * 33 * 128 * 2;  // 35.7 MB (128 imgs)
    __hip_bfloat16* act1 = (__hip_bfloat16*)alloc(act1_bytes);
    __hip_bfloat16* act2 = (__hip_bfloat16*)alloc(act2_bytes);
    float*          vbuf = (float*)alloc((size_t)256 * 256 * 4);
    float*          w1t  = (float*)alloc((size_t)1728 * 4);
    __hip_bfloat16* w2t  = (__hip_bfloat16*)alloc((size_t)73728 * 2);
    __hip_bfloat16* w3t  = (__hip_bfloat16*)alloc((size_t)294912 * 2);

    // zero halos (interiors overwritten every use) + pool accumulator
    (void)hipMemsetAsync(act1, 0, act1_bytes, stream);
    (void)hipMemsetAsync(act2, 0, act2_bytes, stream);
    (void)hipMemsetAsync(vbuf, 0, (size_t)256 * 256 * 4, stream);

    transpose_w1_kernel<<<DIV_UP(1728, 256), 256, 0, stream>>>(c1_w, w1t);
    repack_w_kernel<<<DIV_UP(73728, 256), 256, 0, stream>>>(c2_w, w2t, 128, 64);
    repack_w_kernel<<<DIV_UP(294912, 256), 256, 0, stream>>>(c3_w, w3t, 256, 128);

    for (int c0 = 0; c0 < 256; c0 += 128) {
        for (int s0 = 0; s0 < 128; s0 += 64) {
            const float* img_c = images + (size_t)(c0 + s0) * 3 * 128 * 128;
            conv1_kernel<<<dim3(16, 64), dim3(64, 4), 0, stream>>>(
                img_c, w1t, c1_b, act1);
            conv2_gemm_kernel<<<dim3(512), 256, 0, stream>>>(
                act1, w2t, c2_b, act2 + (size_t)s0 * 33 * 33 * 128);
        }
        // conv3 over 128 images: M = 32768 -> 256 Mt x 2 N-tiles = 512 blocks
        conv3_gemm_pool_kernel<<<dim3(256, 2), 256, 0, stream>>>(
            act2, w3t, c3_b, vbuf + (size_t)c0 * 256);
    }
    tail_kernel<<<256, 256, 0, stream>>>(prop, task_ids, p1_w, p1_b, p2_w, p2_b,
                                         vbuf, f1_w, f1_b, f2_w, f2_b, temb,
                                         g_w, g_b, h1_w, h1_b, h2_w, h2_b,
                                         h3_w, h3_b, out);
}